// Round 5
// baseline (297.016 us; speedup 1.0000x reference)
//
#include <hip/hip_runtime.h>
#include <hip/hip_bf16.h>

#define AS1 __attribute__((address_space(1)))
#define AS3 __attribute__((address_space(3)))

typedef __attribute__((ext_vector_type(8))) short bf16x8v;   // 8 bf16 (4 VGPRs)
typedef __attribute__((ext_vector_type(4))) short bf16x4v;   // 4 bf16 (2 VGPRs)
typedef __attribute__((ext_vector_type(4))) float f32x4;

#define MFMA32 __builtin_amdgcn_mfma_f32_16x16x32_bf16
#define MFMA16 __builtin_amdgcn_mfma_f32_16x16x16bf16_1k

__device__ __forceinline__ short f2bf(float f) {
  __hip_bfloat16 h = __float2bfloat16(f);          // RNE
  return *reinterpret_cast<short*>(&h);
}
__device__ __forceinline__ bf16x4v cvt4(f32x4 v) {
  bf16x4v r; r[0]=f2bf(v[0]); r[1]=f2bf(v[1]); r[2]=f2bf(v[2]); r[3]=f2bf(v[3]);
  return r;
}
__device__ __forceinline__ bf16x8v cvt8(float4 a, float4 b) {
  bf16x8v r;
  r[0]=f2bf(a.x); r[1]=f2bf(a.y); r[2]=f2bf(a.z); r[3]=f2bf(a.w);
  r[4]=f2bf(b.x); r[5]=f2bf(b.y); r[6]=f2bf(b.z); r[7]=f2bf(b.w);
  return r;
}

// ---------------------------------------------------------------------------
// prep: bf16 Wq/Wk/Wv (row-major) + Wfc in MFMA-B-fragment order:
// block (ct,k0) of 1KB holds lane-ordered 16B slices so a wave's B-frag load
// is ONE contiguous 1KB global_load_dwordx4.
//   src Wfc[r][c] -> dst (((r>>4)*32 + (c>>5))*512) + (((c>>3)&3)*16+(r&15))*8 + (c&7)
// ---------------------------------------------------------------------------
__global__ void prep_kernel(const float* __restrict__ Wq, const float* __restrict__ Wk,
                            const float* __restrict__ Wv, const float* __restrict__ Wfc,
                            __hip_bfloat16* __restrict__ Wqb, __hip_bfloat16* __restrict__ Wkb,
                            __hip_bfloat16* __restrict__ Wvb, __hip_bfloat16* __restrict__ Wfcf)
{
  int i = blockIdx.x * blockDim.x + threadIdx.x;
  if (i < 64 * 64) {
    Wqb[i] = __float2bfloat16(Wq[i]);
    Wkb[i] = __float2bfloat16(Wk[i]);
    Wvb[i] = __float2bfloat16(Wv[i]);
  }
  for (int j = i; j < 1024 * 1024; j += gridDim.x * blockDim.x) {
    const int r = j >> 10, c = j & 1023;
    const int dst = (((r >> 4) * 32 + (c >> 5)) * 512) +
                    ((((c >> 3) & 3) * 16 + (r & 15)) * 8) + (c & 7);
    Wfcf[dst] = __float2bfloat16(Wfc[j]);
  }
}

// ---------------------------------------------------------------------------
// fused_kernel: 512 blocks x 4 waves x 32 tokens.
// Phase 1 (per wave, 8 tokens): reg-path loads, all-MFMA attn (r3 math),
//   PV output -> swizzled LDS X-tile (bf16), NO global X traffic.
// Phase 2: C[32][1024] = X @ Wfc^T + bfc. A-frags: ds_read_b128 from X
//   (XOR ^((t&7)<<4) -> conflict-free); B-frags: 1KB-linear loads from
//   fragment-ordered Wfcf (L2-resident); 1024 MFMA/wave; f32 out coalesced.
// ---------------------------------------------------------------------------
struct TokL {
  float4 qa0, qb0, qa1, qb1;
  float4 ka0, kb0, ka1, kb1;
  float4 va0, vb0, va1, vb1;
};

__global__ __launch_bounds__(256) void fused_kernel(
    const float* __restrict__ Vin, const float* __restrict__ Kin,
    const float* __restrict__ Qin,
    const __hip_bfloat16* __restrict__ Wvb, const __hip_bfloat16* __restrict__ Wkb,
    const __hip_bfloat16* __restrict__ Wqb,
    const float* __restrict__ bv, const float* __restrict__ bk,
    const float* __restrict__ bq,
    const __hip_bfloat16* __restrict__ Wfcf, const float* __restrict__ bfc,
    float* __restrict__ out)
{
  __shared__ __hip_bfloat16 Xs[32 * 1024];           // 64 KB, swizzled
  char* xchar = (char*)Xs;
  const int wid = threadIdx.x >> 6, lane = threadIdx.x & 63;
  const int lo = lane & 15, hi = lane >> 4;
  const int tokb = blockIdx.x * 32;                  // block's 32 tokens
  const int t0 = wid * 8;                            // wave's local tokens
  const int xoff = lo * 64 + hi * 8;

  // ---------------- phase 1: attention into LDS ----------------
  {
    bf16x8v wqf[4][2], wkf[4][2], wvf[4][2];
#pragma unroll
    for (int i = 0; i < 4; ++i)
#pragma unroll
      for (int ks = 0; ks < 2; ++ks) {
        const int off = (i * 16 + lo) * 64 + ks * 32 + hi * 8;
        wqf[i][ks] = *(const bf16x8v*)(Wqb + off);
        wkf[i][ks] = *(const bf16x8v*)(Wkb + off);
        wvf[i][ks] = *(const bf16x8v*)(Wvb + off);
      }
    float4 bq4[4], bk4[4]; float bvv[4];
#pragma unroll
    for (int i = 0; i < 4; ++i) {
      bq4[i] = *(const float4*)(bq + i * 16 + hi * 4);
      bk4[i] = *(const float4*)(bk + i * 16 + hi * 4);
      bvv[i] = bv[i * 16 + lo];
    }

    auto load_tok = [&](int n, TokL& L) {
      const size_t tb = (size_t)(tokb + t0 + n) * 1024;
      const float* qp = Qin + tb + xoff;
      const float* kp = Kin + tb + xoff;
      const float* vp = Vin + tb + xoff;
      L.qa0 = *(const float4*)(qp);      L.qb0 = *(const float4*)(qp + 4);
      L.qa1 = *(const float4*)(qp + 32); L.qb1 = *(const float4*)(qp + 36);
      L.ka0 = *(const float4*)(kp);      L.kb0 = *(const float4*)(kp + 4);
      L.ka1 = *(const float4*)(kp + 32); L.kb1 = *(const float4*)(kp + 36);
      L.va0 = *(const float4*)(vp);      L.vb0 = *(const float4*)(vp + 4);
      L.va1 = *(const float4*)(vp + 32); L.vb1 = *(const float4*)(vp + 36);
    };

    auto compute_tok = [&](int n, const TokL& L) {
      bf16x8v xq0 = cvt8(L.qa0, L.qb0), xq1 = cvt8(L.qa1, L.qb1);
      bf16x8v xk0 = cvt8(L.ka0, L.kb0), xk1 = cvt8(L.ka1, L.kb1);

      f32x4 qt[4], kt[4];
#pragma unroll
      for (int i = 0; i < 4; ++i) {
        f32x4 aq = { bq4[i].x, bq4[i].y, bq4[i].z, bq4[i].w };
        aq = MFMA32(wqf[i][0], xq0, aq, 0, 0, 0);
        aq = MFMA32(wqf[i][1], xq1, aq, 0, 0, 0);
        qt[i] = aq;
        f32x4 ak = { bk4[i].x, bk4[i].y, bk4[i].z, bk4[i].w };
        ak = MFMA32(wkf[i][0], xk0, ak, 0, 0, 0);
        ak = MFMA32(wkf[i][1], xk1, ak, 0, 0, 0);
        kt[i] = ak;
      }

      f32x4 ea = { 0.f, 0.f, 0.f, 0.f }, eb = { 0.f, 0.f, 0.f, 0.f };
      ea = MFMA16(cvt4(kt[0]), cvt4(qt[0]), ea, 0, 0, 0);
      eb = MFMA16(cvt4(kt[1]), cvt4(qt[1]), eb, 0, 0, 0);
      ea = MFMA16(cvt4(kt[2]), cvt4(qt[2]), ea, 0, 0, 0);
      eb = MFMA16(cvt4(kt[3]), cvt4(qt[3]), eb, 0, 0, 0);
      f32x4 e = ea + eb;                 // e[j] = E[h=lo][g=hi*4+j]

      float mx = fmaxf(fmaxf(e[0], e[1]), fmaxf(e[2], e[3]));
      mx = fmaxf(mx, __shfl_xor(mx, 16));
      mx = fmaxf(mx, __shfl_xor(mx, 32));
      float p0 = __expf((e[0] - mx) * 0.125f);
      float p1 = __expf((e[1] - mx) * 0.125f);
      float p2 = __expf((e[2] - mx) * 0.125f);
      float p3 = __expf((e[3] - mx) * 0.125f);
      float s = p0 + p1 + p2 + p3;
      s += __shfl_xor(s, 16);
      s += __shfl_xor(s, 32);
      const float inv = 1.0f / s;
      bf16x4v pa;
      pa[0] = f2bf(p0 * inv); pa[1] = f2bf(p1 * inv);
      pa[2] = f2bf(p2 * inv); pa[3] = f2bf(p3 * inv);

      bf16x8v xv0 = cvt8(L.va0, L.vb0), xv1 = cvt8(L.va1, L.vb1);
      f32x4 vc[4];
#pragma unroll
      for (int i = 0; i < 4; ++i) {
        f32x4 av = { bvv[i], bvv[i], bvv[i], bvv[i] };
        av = MFMA32(xv0, wvf[i][0], av, 0, 0, 0);
        av = MFMA32(xv1, wvf[i][1], av, 0, 0, 0);
        vc[i] = av;
      }

      // O -> LDS, swizzled: token t = t0+n, feature f = (hi*4+j)*64+ni*16+lo
      const int tl = t0 + n;
      const int tb2 = tl * 2048;
      const int sw = (tl & 7) << 4;
#pragma unroll
      for (int ni = 0; ni < 4; ++ni) {
        f32x4 z = { 0.f, 0.f, 0.f, 0.f };
        z = MFMA16(pa, cvt4(vc[ni]), z, 0, 0, 0);
#pragma unroll
        for (int j = 0; j < 4; ++j) {
          const int fbyte = ((hi * 4 + j) * 64 + ni * 16 + lo) * 2;
          *(short*)(xchar + ((tb2 + fbyte) ^ sw)) = f2bf(z[j]);
        }
      }
    };

    TokL A, B;
    load_tok(0, A);
    load_tok(1, B);
    compute_tok(0, A);
    load_tok(2, A);
    compute_tok(1, B);
    load_tok(3, B);
    compute_tok(2, A);
    load_tok(4, A);
    compute_tok(3, B);
    load_tok(5, B);
    compute_tok(4, A);
    load_tok(6, A);
    compute_tok(5, B);
    load_tok(7, B);
    compute_tok(6, A);
    compute_tok(7, B);
  }

  __syncthreads();

  // ---------------- phase 2: FC  C[32][1024] = X @ Wfc^T + bfc ----------------
  {
    const int wc = wid;                      // wave's 256-col strip
    float bsv[16];
#pragma unroll
    for (int ni = 0; ni < 16; ++ni) bsv[ni] = bfc[wc * 256 + ni * 16 + lo];

    f32x4 acc0[16], acc1[16];
#pragma unroll
    for (int ni = 0; ni < 16; ++ni) {
      acc0[ni] = (f32x4){0.f, 0.f, 0.f, 0.f};
      acc1[ni] = (f32x4){0.f, 0.f, 0.f, 0.f};
    }

    const __hip_bfloat16* bp0 = Wfcf + (size_t)(wc * 16) * 32 * 512 + lane * 8;

#pragma unroll 2
    for (int k0 = 0; k0 < 32; ++k0) {
      const int kb = k0 * 64 + hi * 16;      // byte offset of k-slice
      bf16x8v a0 = *(const bf16x8v*)(xchar + ((lo * 2048 + kb) ^ ((lo & 7) << 4)));
      bf16x8v a1 = *(const bf16x8v*)(xchar + (((16 + lo) * 2048 + kb) ^ ((lo & 7) << 4)));
      const __hip_bfloat16* bp = bp0 + k0 * 512;
#pragma unroll
      for (int ni = 0; ni < 16; ++ni) {
        bf16x8v bfrag = *(const bf16x8v*)(bp + (size_t)ni * 32 * 512);
        acc0[ni] = MFMA32(a0, bfrag, acc0[ni], 0, 0, 0);
        acc1[ni] = MFMA32(a1, bfrag, acc1[ni], 0, 0, 0);
      }
    }

    // epilogue: row = tokb + rt*16 + hi*4 + j, col = wc*256 + ni*16 + lo
    float* o0 = out + (size_t)(tokb + hi * 4) * 1024 + wc * 256 + lo;
    float* o1 = out + (size_t)(tokb + 16 + hi * 4) * 1024 + wc * 256 + lo;
#pragma unroll
    for (int ni = 0; ni < 16; ++ni) {
#pragma unroll
      for (int j = 0; j < 4; ++j) {
        o0[(size_t)j * 1024 + ni * 16] = acc0[ni][j] + bsv[ni];
        o1[(size_t)j * 1024 + ni * 16] = acc1[ni][j] + bsv[ni];
      }
    }
  }
}

// ---------------------------------------------------------------------------
extern "C" void kernel_launch(void* const* d_in, const int* in_sizes, int n_in,
                              void* d_out, int out_size, void* d_ws, size_t ws_size,
                              hipStream_t stream)
{
  const float* value = (const float*)d_in[0];
  const float* key   = (const float*)d_in[1];
  const float* query = (const float*)d_in[2];
  const float* Wv  = (const float*)d_in[3];
  const float* bv  = (const float*)d_in[4];
  const float* Wk  = (const float*)d_in[5];
  const float* bk  = (const float*)d_in[6];
  const float* Wq  = (const float*)d_in[7];
  const float* bq  = (const float*)d_in[8];
  const float* Wfc = (const float*)d_in[9];
  const float* bfc = (const float*)d_in[10];
  float* out = (float*)d_out;

  char* ws = (char*)d_ws;
  __hip_bfloat16* Wfcf = (__hip_bfloat16*)ws;                 // 2 MiB
  __hip_bfloat16* Wqb  = (__hip_bfloat16*)(ws + 2097152);     // 8 KiB each
  __hip_bfloat16* Wkb  = Wqb + 4096;
  __hip_bfloat16* Wvb  = Wkb + 4096;

  prep_kernel<<<4096, 256, 0, stream>>>(Wq, Wk, Wv, Wfc, Wqb, Wkb, Wvb, Wfcf);
  fused_kernel<<<512, 256, 0, stream>>>(value, key, query, Wvb, Wkb, Wqb,
                                        bv, bk, bq, Wfcf, bfc, out);
}

// Round 6
// 104.380 us; speedup vs baseline: 2.8455x; 2.8455x over previous
//
#include <hip/hip_runtime.h>
#include <hip/hip_bf16.h>

#define AS1 __attribute__((address_space(1)))
#define AS3 __attribute__((address_space(3)))

typedef __attribute__((ext_vector_type(8))) short bf16x8v;   // 8 bf16 (4 VGPRs)
typedef __attribute__((ext_vector_type(4))) short bf16x4v;   // 4 bf16 (2 VGPRs)
typedef __attribute__((ext_vector_type(4))) float f32x4;

#define MFMA32 __builtin_amdgcn_mfma_f32_16x16x32_bf16
#define MFMA16 __builtin_amdgcn_mfma_f32_16x16x16bf16_1k

__device__ __forceinline__ short f2bf(float f) {
  __hip_bfloat16 h = __float2bfloat16(f);          // RNE
  return *reinterpret_cast<short*>(&h);
}
__device__ __forceinline__ bf16x4v cvt4(f32x4 v) {
  bf16x4v r; r[0]=f2bf(v[0]); r[1]=f2bf(v[1]); r[2]=f2bf(v[2]); r[3]=f2bf(v[3]);
  return r;
}
__device__ __forceinline__ bf16x8v cvt8(float4 a, float4 b) {
  bf16x8v r;
  r[0]=f2bf(a.x); r[1]=f2bf(a.y); r[2]=f2bf(a.z); r[3]=f2bf(a.w);
  r[4]=f2bf(b.x); r[5]=f2bf(b.y); r[6]=f2bf(b.z); r[7]=f2bf(b.w);
  return r;
}

// ---------------------------------------------------------------------------
// prep: (a) Wq/Wk/Wv -> MFMA-fragment order (one 24KB block: Wq|Wk|Wv),
//       frag (i,ks) = 1KB holding lane-ordered 16B slices:
//         src (r,c) -> ((r>>4)*2 + (c>>5))*512 + ((((c>>3)&3)*16 + (r&15))*8) + (c&7)
//       (same transform valid for A-use (Wq,Wk) and B-use (Wv));
//       (b) Wfc -> bf16 row-major for the tiled GEMM.
// ---------------------------------------------------------------------------
__global__ void prep_kernel(const float* __restrict__ Wq, const float* __restrict__ Wk,
                            const float* __restrict__ Wv, const float* __restrict__ Wfc,
                            __hip_bfloat16* __restrict__ Wfrag,
                            __hip_bfloat16* __restrict__ Wfcb)
{
  int i = blockIdx.x * blockDim.x + threadIdx.x;
  if (i < 64 * 64) {
    const int r = i >> 6, c = i & 63;
    const int dst = (((r >> 4) * 2 + (c >> 5)) * 512) +
                    ((((c >> 3) & 3) * 16 + (r & 15)) * 8) + (c & 7);
    Wfrag[dst]        = __float2bfloat16(Wq[i]);
    Wfrag[4096 + dst] = __float2bfloat16(Wk[i]);
    Wfrag[8192 + dst] = __float2bfloat16(Wv[i]);
  }
  for (int j = i; j < 1024 * 1024; j += gridDim.x * blockDim.x)
    Wfcb[j] = __float2bfloat16(Wfc[j]);
}

// ---------------------------------------------------------------------------
// attn_kernel: 1024 blocks x 4 waves x 4 tokens. Weight fragments live in
// LDS (24KB/block, staged once via global_load_lds, ds_read_b128 per use) --
// removes the ~96-VGPR persistent weight state that caused remat/spill in
// r2-r4 (VGPR_Count 108-124 << ~230 needed). Sequential per-token chain;
// latency hidden by wave overlap now that registers fit.
// ---------------------------------------------------------------------------
__global__ __launch_bounds__(256) void attn_kernel(
    const float* __restrict__ Vin, const float* __restrict__ Kin,
    const float* __restrict__ Qin,
    const __hip_bfloat16* __restrict__ Wfrag,
    const float* __restrict__ bv, const float* __restrict__ bk,
    const float* __restrict__ bq,
    __hip_bfloat16* __restrict__ Xout)
{
  __shared__ __hip_bfloat16 wlds[12288];    // 24KB: Wq | Wk | Wv frag-ordered
  const int wid = threadIdx.x >> 6, lane = threadIdx.x & 63;
  const int lo = lane & 15, hi = lane >> 4;
  const int tok0 = (blockIdx.x * 4 + wid) * 4;
  const int xoff = lo * 64 + hi * 8;

  // stage 24KB of weights: wave wid stages chunks wid*6 .. wid*6+5 (1KB each)
#pragma unroll
  for (int c = 0; c < 6; ++c) {
    const int ch = wid * 6 + c;
    __builtin_amdgcn_global_load_lds((const AS1 void*)(Wfrag + ch * 512 + lane * 8),
                                     (AS3 void*)(wlds + ch * 512), 16, 0, 0);
  }
  float4 bq4[4], bk4[4]; float bvv[4];
#pragma unroll
  for (int i = 0; i < 4; ++i) {
    bq4[i] = *(const float4*)(bq + i * 16 + hi * 4);
    bk4[i] = *(const float4*)(bk + i * 16 + hi * 4);
    bvv[i] = bv[i * 16 + lo];
  }
  asm volatile("s_waitcnt vmcnt(0)" ::: "memory");
  __syncthreads();

  const char* wq_b = (const char*)wlds;            // frag (i,ks) at (i*2+ks)*1024
  const char* wk_b = (const char*)(wlds + 4096);
  const char* wv_b = (const char*)(wlds + 8192);
  const int lb = lane * 16;                        // lane byte offset in a frag

#pragma unroll 1
  for (int n = 0; n < 4; ++n) {
    const size_t tb = (size_t)(tok0 + n) * 1024;
    const float* qp = Qin + tb + xoff;
    const float* kp = Kin + tb + xoff;
    const float* vp = Vin + tb + xoff;
    float4 qa0 = *(const float4*)(qp),      qb0 = *(const float4*)(qp + 4);
    float4 qa1 = *(const float4*)(qp + 32), qb1 = *(const float4*)(qp + 36);
    float4 ka0 = *(const float4*)(kp),      kb0 = *(const float4*)(kp + 4);
    float4 ka1 = *(const float4*)(kp + 32), kb1 = *(const float4*)(kp + 36);
    float4 va0 = *(const float4*)(vp),      vb0 = *(const float4*)(vp + 4);
    float4 va1 = *(const float4*)(vp + 32), vb1 = *(const float4*)(vp + 36);
    bf16x8v xq0 = cvt8(qa0, qb0), xq1 = cvt8(qa1, qb1);
    bf16x8v xk0 = cvt8(ka0, kb0), xk1 = cvt8(ka1, kb1);
    bf16x8v xv0 = cvt8(va0, vb0), xv1 = cvt8(va1, vb1);

    // projections qT/kT: per d-block i, C row = d = i*16+hi*4+j, col = h = lo
    f32x4 qt[4], kt[4];
#pragma unroll
    for (int i = 0; i < 4; ++i) {
      bf16x8v wq0 = *(const bf16x8v*)(wq_b + (i * 2 + 0) * 1024 + lb);
      bf16x8v wq1 = *(const bf16x8v*)(wq_b + (i * 2 + 1) * 1024 + lb);
      f32x4 aq = { bq4[i].x, bq4[i].y, bq4[i].z, bq4[i].w };
      aq = MFMA32(wq0, xq0, aq, 0, 0, 0);
      aq = MFMA32(wq1, xq1, aq, 0, 0, 0);
      qt[i] = aq;
      bf16x8v wk0 = *(const bf16x8v*)(wk_b + (i * 2 + 0) * 1024 + lb);
      bf16x8v wk1 = *(const bf16x8v*)(wk_b + (i * 2 + 1) * 1024 + lb);
      f32x4 ak = { bk4[i].x, bk4[i].y, bk4[i].z, bk4[i].w };
      ak = MFMA32(wk0, xk0, ak, 0, 0, 0);
      ak = MFMA32(wk1, xk1, ak, 0, 0, 0);
      kt[i] = ak;
    }

    // E' = K@Q^T over 4 d-blocks; e[j] = E[h=lo][g=hi*4+j]
    f32x4 ea = { 0.f, 0.f, 0.f, 0.f }, eb = { 0.f, 0.f, 0.f, 0.f };
    ea = MFMA16(cvt4(kt[0]), cvt4(qt[0]), ea, 0, 0, 0);
    eb = MFMA16(cvt4(kt[1]), cvt4(qt[1]), eb, 0, 0, 0);
    ea = MFMA16(cvt4(kt[2]), cvt4(qt[2]), ea, 0, 0, 0);
    eb = MFMA16(cvt4(kt[3]), cvt4(qt[3]), eb, 0, 0, 0);
    f32x4 e = ea + eb;

    // softmax over g
    float mx = fmaxf(fmaxf(e[0], e[1]), fmaxf(e[2], e[3]));
    mx = fmaxf(mx, __shfl_xor(mx, 16));
    mx = fmaxf(mx, __shfl_xor(mx, 32));
    float p0 = __expf((e[0] - mx) * 0.125f);
    float p1 = __expf((e[1] - mx) * 0.125f);
    float p2 = __expf((e[2] - mx) * 0.125f);
    float p3 = __expf((e[3] - mx) * 0.125f);
    float s = p0 + p1 + p2 + p3;
    s += __shfl_xor(s, 16);
    s += __shfl_xor(s, 32);
    const float inv = 1.0f / s;
    bf16x4v pa;
    pa[0] = f2bf(p0 * inv); pa[1] = f2bf(p1 * inv);
    pa[2] = f2bf(p2 * inv); pa[3] = f2bf(p3 * inv);

    // v-projection: row g=hi*4+j, col dv=i*16+lo
    f32x4 vc[4];
#pragma unroll
    for (int i = 0; i < 4; ++i) {
      bf16x8v wv0 = *(const bf16x8v*)(wv_b + (i * 2 + 0) * 1024 + lb);
      bf16x8v wv1 = *(const bf16x8v*)(wv_b + (i * 2 + 1) * 1024 + lb);
      f32x4 av = { bvv[i], bvv[i], bvv[i], bvv[i] };
      av = MFMA32(xv0, wv0, av, 0, 0, 0);
      av = MFMA32(xv1, wv1, av, 0, 0, 0);
      vc[i] = av;
    }

    // O = P @ v ; D row = h = hi*4+j, col = dv = ni*16+lo
    __hip_bfloat16* xo = Xout + tb + (size_t)hi * 4 * 64 + lo;
#pragma unroll
    for (int ni = 0; ni < 4; ++ni) {
      f32x4 z = { 0.f, 0.f, 0.f, 0.f };
      z = MFMA16(pa, cvt4(vc[ni]), z, 0, 0, 0);
#pragma unroll
      for (int j = 0; j < 4; ++j)
        xo[j * 64 + ni * 16] = __float2bfloat16(z[j]);
    }
  }
}

// ---------------------------------------------------------------------------
// gemm_kernel: C = X(bf16) @ Wfc^T + bfc (r4 version, XCD-friendly decode).
// ---------------------------------------------------------------------------
__global__ __launch_bounds__(256) void gemm_kernel(
    const __hip_bfloat16* __restrict__ A,
    const __hip_bfloat16* __restrict__ B,
    const float* __restrict__ bias, float* __restrict__ C)
{
  constexpr int K = 1024, N = 1024;
  __shared__ __hip_bfloat16 Asm[128 * 64];
  __shared__ __hip_bfloat16 Bsm[128 * 64];
  const int tid = threadIdx.x, wid = tid >> 6, lane = tid & 63;
  const int bm = blockIdx.x & 127, bn = blockIdx.x >> 7;
  const int m0 = bm * 128, n0 = bn * 128;
  const int wr = wid >> 1, wc = wid & 1;

  f32x4 acc[4][4];
#pragma unroll
  for (int i = 0; i < 4; ++i)
#pragma unroll
    for (int j = 0; j < 4; ++j) acc[i][j] = (f32x4){0.f, 0.f, 0.f, 0.f};

  const int lrow = lane >> 3;
  const int gcol = ((lane & 7) ^ lrow) * 8;

  for (int kt = 0; kt < K / 64; ++kt) {
    const int k0 = kt * 64;
    __syncthreads();
#pragma unroll
    for (int c = 0; c < 4; ++c) {
      const int ca = wid * 4 + c;
      const int row = ca * 8 + lrow;
      __builtin_amdgcn_global_load_lds(
          (const AS1 void*)(A + (size_t)(m0 + row) * K + k0 + gcol),
          (AS3 void*)((char*)Asm + ca * 1024), 16, 0, 0);
      __builtin_amdgcn_global_load_lds(
          (const AS1 void*)(B + (size_t)(n0 + row) * K + k0 + gcol),
          (AS3 void*)((char*)Bsm + ca * 1024), 16, 0, 0);
    }
    asm volatile("s_waitcnt vmcnt(0)" ::: "memory");
    __syncthreads();

#pragma unroll
    for (int ks = 0; ks < 2; ++ks) {
      bf16x8v af[4], bfr[4];
#pragma unroll
      for (int mi = 0; mi < 4; ++mi) {
        const int arow = wr * 64 + mi * 16 + (lane & 15);
        const int slot = (ks * 4 + (lane >> 4)) ^ (arow & 7);
        af[mi] = *(const bf16x8v*)((const char*)Asm + arow * 128 + slot * 16);
      }
#pragma unroll
      for (int ni = 0; ni < 4; ++ni) {
        const int brow = wc * 64 + ni * 16 + (lane & 15);
        const int slot = (ks * 4 + (lane >> 4)) ^ (brow & 7);
        bfr[ni] = *(const bf16x8v*)((const char*)Bsm + brow * 128 + slot * 16);
      }
#pragma unroll
      for (int mi = 0; mi < 4; ++mi)
#pragma unroll
        for (int ni = 0; ni < 4; ++ni)
          acc[mi][ni] = __builtin_amdgcn_mfma_f32_16x16x32_bf16(
              af[mi], bfr[ni], acc[mi][ni], 0, 0, 0);
    }
  }

#pragma unroll
  for (int mi = 0; mi < 4; ++mi) {
    const int r0 = m0 + wr * 64 + mi * 16 + (lane >> 4) * 4;
#pragma unroll
    for (int ni = 0; ni < 4; ++ni) {
      const int c = n0 + wc * 64 + ni * 16 + (lane & 15);
      const float bs = bias[c];
#pragma unroll
      for (int j = 0; j < 4; ++j)
        C[(size_t)(r0 + j) * N + c] = acc[mi][ni][j] + bs;
    }
  }
}

// ---------------------------------------------------------------------------
extern "C" void kernel_launch(void* const* d_in, const int* in_sizes, int n_in,
                              void* d_out, int out_size, void* d_ws, size_t ws_size,
                              hipStream_t stream)
{
  const float* value = (const float*)d_in[0];
  const float* key   = (const float*)d_in[1];
  const float* query = (const float*)d_in[2];
  const float* Wv  = (const float*)d_in[3];
  const float* bv  = (const float*)d_in[4];
  const float* Wk  = (const float*)d_in[5];
  const float* bk  = (const float*)d_in[6];
  const float* Wq  = (const float*)d_in[7];
  const float* bq  = (const float*)d_in[8];
  const float* Wfc = (const float*)d_in[9];
  const float* bfc = (const float*)d_in[10];
  float* out = (float*)d_out;

  char* ws = (char*)d_ws;
  __hip_bfloat16* Xb    = (__hip_bfloat16*)ws;                        // 32 MiB
  __hip_bfloat16* Wfcb  = (__hip_bfloat16*)(ws + 33554432);           // 2 MiB
  __hip_bfloat16* Wfrag = (__hip_bfloat16*)(ws + 33554432 + 2097152); // 24 KiB

  prep_kernel<<<4096, 256, 0, stream>>>(Wq, Wk, Wv, Wfc, Wfrag, Wfcb);
  attn_kernel<<<1024, 256, 0, stream>>>(value, key, query, Wfrag,
                                        bv, bk, bq, Xb);
  gemm_kernel<<<1024, 256, 0, stream>>>(Xb, Wfcb, bfc, out);
}